// Round 9
// baseline (447.029 us; speedup 1.0000x reference)
//
#include <hip/hip_runtime.h>

constexpr int NN = 50000;
constexpr int NE = 1600000;
constexpr int NG = 1000;
constexpr int NBLK = 196;            // scan blocks: 196*256 = 50176 >= NN
constexpr int NPART = 8;             // XCD count; dst-space partitions
constexpr int PSZ = (NN + NPART - 1) / NPART;   // 6250 nodes per partition
constexpr int MSTRIDE = 72;          // bf16 LDS row stride (64 + 8 pad)

// workspace layout in 4-byte units
constexpr int OFF_DEG   = 0;          // int[50176]  (zeroed)
constexpr int OFF_SUMS  = 50176;      // f32[64000]  (zeroed)
constexpr int OFF_CNT   = 114176;     // f32[1024]   (zeroed)
constexpr int ZERO_UNITS= 115200;
constexpr int OFF_OFFS  = 115200;     // int[50176]
constexpr int OFF_CURS  = 165376;     // int[50176]
constexpr int OFF_BTOT  = 215552;     // int[256]
constexpr int OFF_BEXCL = 215808;     // int[256]
constexpr int OFF_SE4   = 216064;     // int4[NE] = 6400000 units (16B aligned)
constexpr int OFF_H1    = 6616064;    // bf16[NN*64] = 1600000 units
constexpr int OFF_Z     = 8216064;    // bf16[NN*64] = 1600000 units (packed 2/uint)
// end = 9,816,064 units = 39.3 MB

typedef __attribute__((ext_vector_type(8))) short short8;     // 8 bf16 (4 VGPRs)
typedef __attribute__((ext_vector_type(4))) float float4v;    // MFMA accumulator

__device__ __forceinline__ unsigned int f2bf(float f) {   // RNE fp32->bf16 bits
    unsigned int u = __float_as_uint(f);
    return (u + 0x7fffu + ((u >> 16) & 1u)) >> 16;
}
__device__ __forceinline__ float bf2f_lo(unsigned int p) { return __uint_as_float(p << 16); }
__device__ __forceinline__ float bf2f_hi(unsigned int p) { return __uint_as_float(p & 0xffff0000u); }

// ---------- degree histogram ----------
__global__ __launch_bounds__(256) void hist_kernel(const int* __restrict__ eidx,
                                                   int* __restrict__ deg) {
    int tid = blockIdx.x * 256 + threadIdx.x;
    int stride = gridDim.x * 256;
    for (int e = tid; e < NE; e += stride) atomicAdd(&deg[eidx[NE + e]], 1);
}

__global__ __launch_bounds__(256) void scanA_kernel(const int* __restrict__ deg,
                                                    int* __restrict__ offs,
                                                    int* __restrict__ btot) {
    __shared__ int s[256];
    int t = threadIdx.x;
    int i = blockIdx.x * 256 + t;
    int v = (i < NN) ? deg[i] : 0;
    s[t] = v; __syncthreads();
    for (int o = 1; o < 256; o <<= 1) {
        int u = (t >= o) ? s[t - o] : 0;
        __syncthreads();
        s[t] += u;
        __syncthreads();
    }
    offs[i] = s[t] - v;
    if (t == 255) btot[blockIdx.x] = s[255];
}

__global__ __launch_bounds__(256) void scanB_kernel(const int* __restrict__ btot,
                                                    int* __restrict__ bexcl) {
    __shared__ int s[256];
    int t = threadIdx.x;
    int v = (t < NBLK) ? btot[t] : 0;
    s[t] = v; __syncthreads();
    for (int o = 1; o < 256; o <<= 1) {
        int u = (t >= o) ? s[t - o] : 0;
        __syncthreads();
        s[t] += u;
        __syncthreads();
    }
    bexcl[t] = s[t] - v;
}

__global__ __launch_bounds__(256) void scanC_kernel(int* __restrict__ offs,
                                                    const int* __restrict__ bexcl,
                                                    int* __restrict__ cursor) {
    int i = blockIdx.x * 256 + threadIdx.x;
    int o = offs[i] + bexcl[blockIdx.x];
    offs[i] = o;
    cursor[i] = o;
}

// ---------- XCD-partitioned scatter into CSR ----------
__global__ __launch_bounds__(256) void scatter_kernel(const int* __restrict__ eidx,
                                                      const float4* __restrict__ ea,
                                                      int* __restrict__ cursor,
                                                      int4* __restrict__ se4) {
    const int part = blockIdx.x & (NPART - 1);
    const int lo = part * PSZ, hi = lo + PSZ;
    const int gb = blockIdx.x >> 3;
    const int tid = gb * 256 + threadIdx.x;
    const int stride = (gridDim.x >> 3) * 256;
    for (int e = tid; e < NE; e += stride) {
        int dst = eidx[NE + e];
        if (dst < lo || dst >= hi) continue;
        int src = eidx[e];
        float4 a = ea[e];
        int4 p;
        p.x = src;
        p.y = (int)(f2bf(a.x) | (f2bf(a.y) << 16));
        p.z = (int)(f2bf(a.z) | (f2bf(a.w) << 16));
        p.w = 0;
        int pos = atomicAdd(&cursor[dst], 1);
        se4[pos] = p;
    }
}

// ---------- Layer 1 fused: aggregate (8 edges x 8 dims, 2 batches in flight) + MLP ----------
__global__ __launch_bounds__(256) void layer1_kernel(
    const float* __restrict__ x, const int4* __restrict__ se4,
    const int* __restrict__ offs,
    const float* __restrict__ We1, const float* __restrict__ be1,
    const float* __restrict__ W1a, const float* __restrict__ b1a,
    const float* __restrict__ W1b, const float* __restrict__ b1b,
    unsigned short* __restrict__ h1)
{
    __shared__ float sWe[32];
    __shared__ float sbe[8];
    __shared__ float sWa[7 * 64];
    __shared__ float sWb[64 * 64];
    __shared__ float sba[64], sbb[64];
    __shared__ float tbuf[4][64];
    int tid = threadIdx.x;
    if (tid < 32) { int k = tid >> 3, dd = tid & 7; sWe[tid] = (dd < 7) ? We1[k * 7 + dd] : 0.f; }
    if (tid < 8)  sbe[tid] = (tid < 7) ? be1[tid] : 0.f;
    for (int i = tid; i < 7 * 64; i += 256) sWa[i] = W1a[i];
    for (int i = tid; i < 64 * 64; i += 256) sWb[i] = W1b[i];
    if (tid < 64) { sba[tid] = b1a[tid]; sbb[tid] = b1b[tid]; }
    __syncthreads();

    const int w = tid >> 6, lane = tid & 63;
    const int jg = lane >> 3, d = lane & 7;

    for (int n = blockIdx.x * 4 + w; n < NN; n += gridDim.x * 4) {
        const int off = offs[n];
        const int deg = offs[n + 1] - off;

        float acc = 0.f;
        for (int j0 = 0; j0 < deg; j0 += 16) {
            int ja = j0 + jg;
            int jb = j0 + 8 + jg;
            int4 pa = se4[off + ((ja < deg) ? ja : 0)];
            int4 pb = se4[off + ((jb < deg) ? jb : 0)];
            float xa = (d < 7) ? x[(size_t)pa.x * 7 + d] : 0.f;
            float xb = (d < 7) ? x[(size_t)pb.x * 7 + d] : 0.f;
            float va = sbe[d] + bf2f_lo((unsigned)pa.y) * sWe[d] + bf2f_hi((unsigned)pa.y) * sWe[8 + d]
                     + bf2f_lo((unsigned)pa.z) * sWe[16 + d] + bf2f_hi((unsigned)pa.z) * sWe[24 + d] + xa;
            float vb = sbe[d] + bf2f_lo((unsigned)pb.y) * sWe[d] + bf2f_hi((unsigned)pb.y) * sWe[8 + d]
                     + bf2f_lo((unsigned)pb.z) * sWe[16 + d] + bf2f_hi((unsigned)pb.z) * sWe[24 + d] + xb;
            va = (d < 7 && ja < deg) ? fmaxf(va, 0.f) : 0.f;
            vb = (d < 7 && jb < deg) ? fmaxf(vb, 0.f) : 0.f;
            acc += va + vb;
        }
        acc += __shfl_xor(acc, 8);
        acc += __shfl_xor(acc, 16);
        acc += __shfl_xor(acc, 32);
        float zl = ((d < 7) ? x[(size_t)n * 7 + d] : 0.f) + acc;

        float t = sba[lane];
        #pragma unroll
        for (int k = 0; k < 7; ++k) t += __shfl(zl, k) * sWa[k * 64 + lane];
        t = fmaxf(t, 0.f);
        tbuf[w][lane] = t;
        float o = sbb[lane];
        #pragma unroll 8
        for (int k = 0; k < 64; ++k) o += tbuf[w][k] * sWb[k * 64 + lane];
        h1[(size_t)n * 64 + lane] = (unsigned short)f2bf(fmaxf(o, 0.f));
    }
}

// ---------- Layer 2 aggregation: 2 dims/lane, 16 edges (8 dword gathers) in flight ----------
__global__ __launch_bounds__(256) void aggr2_kernel(
    const unsigned int* __restrict__ h1u, const int4* __restrict__ se4,
    const int* __restrict__ offs,
    const float* __restrict__ We2, const float* __restrict__ be2,
    unsigned int* __restrict__ zb)
{
    __shared__ float sWe[256];
    __shared__ float sbe[64];
    int tid = threadIdx.x;
    sWe[tid] = We2[tid];
    if (tid < 64) sbe[tid] = be2[tid];
    __syncthreads();
    const int w = tid >> 6, lane = tid & 63;
    const int l = lane & 31;
    const int half8 = (lane >> 5) << 3;
    const int n = blockIdx.x * 4 + w;
    const int off = offs[n];
    const int deg = offs[n + 1] - off;
    const float w0x = sWe[2 * l],       w0y = sWe[2 * l + 1];
    const float w1x = sWe[64 + 2 * l],  w1y = sWe[64 + 2 * l + 1];
    const float w2x = sWe[128 + 2 * l], w2y = sWe[128 + 2 * l + 1];
    const float w3x = sWe[192 + 2 * l], w3y = sWe[192 + 2 * l + 1];
    const float bbx = sbe[2 * l],       bby = sbe[2 * l + 1];

    float accx = 0.f, accy = 0.f;
    for (int jb = 0; jb < deg; jb += 16) {
        int m = deg - jb;
        int ll = (lane < 16) ? ((lane < m) ? lane : 0) : 0;
        int4 p = se4[off + jb + ll];
        unsigned int g[8];
        #pragma unroll
        for (int k = 0; k < 8; ++k) {
            int mk = k + half8;
            int sk = __shfl(p.x, (mk < m) ? mk : 0);
            g[k] = h1u[(size_t)sk * 32 + l];
        }
        #pragma unroll
        for (int k = 0; k < 8; ++k) {
            int mk = k + half8;
            int sl = (mk < m) ? mk : 0;
            unsigned int py = (unsigned int)__shfl(p.y, sl);
            unsigned int pz = (unsigned int)__shfl(p.z, sl);
            float e0 = bf2f_lo(py), e1 = bf2f_hi(py);
            float e2 = bf2f_lo(pz), e3 = bf2f_hi(pz);
            float bx = bbx + e0 * w0x + e1 * w1x + e2 * w2x + e3 * w3x;
            float by = bby + e0 * w0y + e1 * w1y + e2 * w2y + e3 * w3y;
            float tx = fmaxf(bf2f_lo(g[k]) + bx, 0.f);
            float ty = fmaxf(bf2f_hi(g[k]) + by, 0.f);
            if (mk < m) { accx += tx; accy += ty; }
        }
    }
    accx += __shfl_xor(accx, 32);
    accy += __shfl_xor(accy, 32);
    if (lane < 32) {
        unsigned int sw = h1u[(size_t)n * 32 + l];
        float zx = bf2f_lo(sw) + accx;
        float zy = bf2f_hi(sw) + accy;
        zb[(size_t)n * 32 + l] = f2bf(zx) | (f2bf(zy) << 16);
    }
}

// ---------- Layer 2 MLP via MFMA + fused global-mean-pool ----------
// 64 nodes/block; A: A[m=lane&15][k=quad*8+j]; C/D: col=lane&15, row=quad*4+reg
__global__ __launch_bounds__(256) void mlp2_kernel(
    const unsigned int* __restrict__ zb,
    const float* __restrict__ W2a, const float* __restrict__ b2a,
    const float* __restrict__ W2b, const float* __restrict__ b2b,
    const int* __restrict__ batch,
    float* __restrict__ sums, float* __restrict__ cnt)
{
    __shared__ __align__(16) unsigned short sZ[64 * MSTRIDE];
    __shared__ __align__(16) unsigned short sT[64 * MSTRIDE];
    __shared__ __align__(16) unsigned short sWaT[64 * MSTRIDE];
    __shared__ __align__(16) unsigned short sWbT[64 * MSTRIDE];
    __shared__ float sba[64], sbb[64];
    const int t = threadIdx.x;
    const int n0 = blockIdx.x * 64;

    // stage transposed bf16 weights + biases + z rows
    for (int i = t; i < 64 * 64; i += 256) {
        int n = i >> 6, k = i & 63;
        sWaT[n * MSTRIDE + k] = (unsigned short)f2bf(W2a[k * 64 + n]);
        sWbT[n * MSTRIDE + k] = (unsigned short)f2bf(W2b[k * 64 + n]);
    }
    if (t < 64) { sba[t] = b2a[t]; sbb[t] = b2b[t]; }
    for (int i = t; i < 64 * 32; i += 256) {
        int node = i >> 5, l = i & 31;
        unsigned int zw = (n0 + node < NN) ? zb[(size_t)(n0 + node) * 32 + l] : 0u;
        *(unsigned int*)&sZ[node * MSTRIDE + 2 * l] = zw;   // low ushort = dim 2l
    }
    if (t < 64 && n0 + t < NN) atomicAdd(&cnt[batch[n0 + t]], 1.0f);
    __syncthreads();

    const int w = t >> 6, lane = t & 63;
    const int qm = lane & 15, quad = lane >> 4;

    // GEMM1: T = relu(Z @ W2a + b2a)
    float4v acc[4];
    #pragma unroll
    for (int nt = 0; nt < 4; ++nt) acc[nt] = (float4v){0.f, 0.f, 0.f, 0.f};
    #pragma unroll
    for (int s = 0; s < 2; ++s) {
        short8 afrag = *(const short8*)&sZ[(w * 16 + qm) * MSTRIDE + s * 32 + quad * 8];
        #pragma unroll
        for (int nt = 0; nt < 4; ++nt) {
            short8 bfrag = *(const short8*)&sWaT[(nt * 16 + qm) * MSTRIDE + s * 32 + quad * 8];
            acc[nt] = __builtin_amdgcn_mfma_f32_16x16x32_bf16(afrag, bfrag, acc[nt], 0, 0, 0);
        }
    }
    #pragma unroll
    for (int nt = 0; nt < 4; ++nt) {
        int n = nt * 16 + qm;
        #pragma unroll
        for (int r = 0; r < 4; ++r) {
            float v = fmaxf(acc[nt][r] + sba[n], 0.f);
            sT[(w * 16 + quad * 4 + r) * MSTRIDE + n] = (unsigned short)f2bf(v);
        }
    }
    __syncthreads();

    // GEMM2: H = relu(T @ W2b + b2b), pooled directly via atomics
    #pragma unroll
    for (int nt = 0; nt < 4; ++nt) acc[nt] = (float4v){0.f, 0.f, 0.f, 0.f};
    #pragma unroll
    for (int s = 0; s < 2; ++s) {
        short8 afrag = *(const short8*)&sT[(w * 16 + qm) * MSTRIDE + s * 32 + quad * 8];
        #pragma unroll
        for (int nt = 0; nt < 4; ++nt) {
            short8 bfrag = *(const short8*)&sWbT[(nt * 16 + qm) * MSTRIDE + s * 32 + quad * 8];
            acc[nt] = __builtin_amdgcn_mfma_f32_16x16x32_bf16(afrag, bfrag, acc[nt], 0, 0, 0);
        }
    }
    #pragma unroll
    for (int r = 0; r < 4; ++r) {
        int node = n0 + w * 16 + quad * 4 + r;
        if (node < NN) {
            int g = batch[node];
            #pragma unroll
            for (int nt = 0; nt < 4; ++nt) {
                int n = nt * 16 + qm;
                float v = fmaxf(acc[nt][r] + sbb[n], 0.f);
                atomicAdd(&sums[(size_t)g * 64 + n], v);
            }
        }
    }
}

// ---------- FC ----------
__global__ __launch_bounds__(256) void fc_kernel(
    const float* __restrict__ sums, const float* __restrict__ cnt,
    const float* __restrict__ Wfc, const float* __restrict__ bfc,
    float* __restrict__ out)
{
    int gid = blockIdx.x * blockDim.x + threadIdx.x;
    if (gid >= NG * 12) return;
    int g = gid / 12, jj = gid - g * 12;
    float inv = 1.f / fmaxf(cnt[g], 1.f);
    float acc = bfc[jj];
    #pragma unroll 8
    for (int k = 0; k < 64; ++k) acc += sums[(size_t)g * 64 + k] * inv * Wfc[k * 12 + jj];
    out[gid] = acc;
}

extern "C" void kernel_launch(void* const* d_in, const int* in_sizes, int n_in,
                              void* d_out, int out_size, void* d_ws, size_t ws_size,
                              hipStream_t stream)
{
    (void)in_sizes; (void)n_in; (void)out_size; (void)ws_size;
    const float*  x    = (const float*)d_in[0];
    const float4* ea   = (const float4*)d_in[1];
    const int*    eidx = (const int*)d_in[2];
    const int*    batch= (const int*)d_in[3];
    const float*  We1  = (const float*)d_in[4];
    const float*  be1  = (const float*)d_in[5];
    const float*  W1a  = (const float*)d_in[6];
    const float*  b1a  = (const float*)d_in[7];
    const float*  W1b  = (const float*)d_in[8];
    const float*  b1b  = (const float*)d_in[9];
    const float*  We2  = (const float*)d_in[10];
    const float*  be2  = (const float*)d_in[11];
    const float*  W2a  = (const float*)d_in[12];
    const float*  b2a  = (const float*)d_in[13];
    const float*  W2b  = (const float*)d_in[14];
    const float*  b2b  = (const float*)d_in[15];
    const float*  Wfc  = (const float*)d_in[16];
    const float*  bfc  = (const float*)d_in[17];
    float* out = (float*)d_out;
    float* ws  = (float*)d_ws;

    int*            deg    = (int*)(ws + OFF_DEG);
    float*          sums   = ws + OFF_SUMS;
    float*          cnt    = ws + OFF_CNT;
    int*            offs   = (int*)(ws + OFF_OFFS);
    int*            cursor = (int*)(ws + OFF_CURS);
    int*            btot   = (int*)(ws + OFF_BTOT);
    int*            bexcl  = (int*)(ws + OFF_BEXCL);
    int4*           se4    = (int4*)(ws + OFF_SE4);
    unsigned short* h1     = (unsigned short*)(ws + OFF_H1);
    unsigned int*   h1u    = (unsigned int*)(ws + OFF_H1);
    unsigned int*   zb     = (unsigned int*)(ws + OFF_Z);

    hipMemsetAsync(d_ws, 0, (size_t)ZERO_UNITS * 4, stream);

    hist_kernel   <<<1024, 256, 0, stream>>>(eidx, deg);
    scanA_kernel  <<<NBLK, 256, 0, stream>>>(deg, offs, btot);
    scanB_kernel  <<<1,    256, 0, stream>>>(btot, bexcl);
    scanC_kernel  <<<NBLK, 256, 0, stream>>>(offs, bexcl, cursor);
    scatter_kernel<<<2048, 256, 0, stream>>>(eidx, ea, cursor, se4);
    layer1_kernel <<<2500, 256, 0, stream>>>(x, se4, offs, We1, be1, W1a, b1a, W1b, b1b, h1);
    aggr2_kernel  <<<12500, 256, 0, stream>>>(h1u, se4, offs, We2, be2, zb);
    mlp2_kernel   <<<(NN + 63) / 64, 256, 0, stream>>>(zb, W2a, b2a, W2b, b2b, batch, sums, cnt);
    fc_kernel     <<<(NG * 12 + 255) / 256, 256, 0, stream>>>(sums, cnt, Wfc, bfc, out);
}

// Round 10
// 379.749 us; speedup vs baseline: 1.1772x; 1.1772x over previous
//
#include <hip/hip_runtime.h>

typedef unsigned char uchar;
typedef unsigned short ushort;
typedef unsigned int uint;

constexpr int NN = 50000;
constexpr int NE = 1600000;
constexpr int NG = 1000;
constexpr int NBLK = 196;            // scan blocks: 196*256 = 50176 >= NN
constexpr int NPART = 8;             // XCD count; dst-space partitions
constexpr int PSZ = (NN + NPART - 1) / NPART;   // 6250
constexpr int MSTRIDE = 72;          // bf16 LDS row stride (64 + 8 pad), 16B-aligned rows

// workspace layout in 4-byte units
constexpr int OFF_DEG   = 0;          // int[50176]  (zeroed)
constexpr int OFF_SUMS  = 50176;      // f32[64000]  (zeroed)
constexpr int OFF_CNT   = 114176;     // f32[1024]   (zeroed)
constexpr int ZERO_UNITS= 115200;
constexpr int OFF_OFFS  = 115200;     // int[50176]
constexpr int OFF_CURS  = 165376;     // int[50176]
constexpr int OFF_BTOT  = 215552;     // int[256]
constexpr int OFF_BEXCL = 215808;     // int[256]
constexpr int OFF_TAG   = 216064;     // uchar[NE] = 400000 units
constexpr int OFF_SE4   = 616064;     // int4[NE] = 6400000 units (byte off %16==0)
constexpr int OFF_Z1    = 7016064;    // f32[NN*8] = 400000 units
constexpr int OFF_H1    = 7416064;    // bf16[NN*64] = 1600000 units
constexpr int OFF_Z     = 9016064;    // packed bf16 uint[NN*32] = 1600000 units
// end = 10,616,064 units = 42.5 MB

typedef __attribute__((ext_vector_type(8))) short short8;     // 8 bf16
typedef __attribute__((ext_vector_type(4))) float float4v;    // MFMA acc

__device__ __forceinline__ uint f2bf(float f) {   // RNE fp32->bf16 bits
    uint u = __float_as_uint(f);
    return (u + 0x7fffu + ((u >> 16) & 1u)) >> 16;
}
__device__ __forceinline__ float bf2f_lo(uint p) { return __uint_as_float(p << 16); }
__device__ __forceinline__ float bf2f_hi(uint p) { return __uint_as_float(p & 0xffff0000u); }

// ---------- degree histogram + partition tag ----------
__global__ __launch_bounds__(256) void hist_kernel(const int* __restrict__ eidx,
                                                   int* __restrict__ deg,
                                                   uchar* __restrict__ tag) {
    int tid = blockIdx.x * 256 + threadIdx.x;
    int stride = gridDim.x * 256;
    for (int e = tid; e < NE; e += stride) {
        int dst = eidx[NE + e];
        atomicAdd(&deg[dst], 1);
        tag[e] = (uchar)(dst / PSZ);
    }
}

__global__ __launch_bounds__(256) void scanA_kernel(const int* __restrict__ deg,
                                                    int* __restrict__ offs,
                                                    int* __restrict__ btot) {
    __shared__ int s[256];
    int t = threadIdx.x;
    int i = blockIdx.x * 256 + t;
    int v = (i < NN) ? deg[i] : 0;
    s[t] = v; __syncthreads();
    for (int o = 1; o < 256; o <<= 1) {
        int u = (t >= o) ? s[t - o] : 0;
        __syncthreads();
        s[t] += u;
        __syncthreads();
    }
    offs[i] = s[t] - v;
    if (t == 255) btot[blockIdx.x] = s[255];
}

__global__ __launch_bounds__(256) void scanB_kernel(const int* __restrict__ btot,
                                                    int* __restrict__ bexcl) {
    __shared__ int s[256];
    int t = threadIdx.x;
    int v = (t < NBLK) ? btot[t] : 0;
    s[t] = v; __syncthreads();
    for (int o = 1; o < 256; o <<= 1) {
        int u = (t >= o) ? s[t - o] : 0;
        __syncthreads();
        s[t] += u;
        __syncthreads();
    }
    bexcl[t] = s[t] - v;
}

__global__ __launch_bounds__(256) void scanC_kernel(int* __restrict__ offs,
                                                    const int* __restrict__ bexcl,
                                                    int* __restrict__ cursor) {
    int i = blockIdx.x * 256 + threadIdx.x;
    int o = offs[i] + bexcl[blockIdx.x];
    offs[i] = o;
    cursor[i] = o;
}

// ---------- XCD-partitioned scatter into CSR (tag-gated) ----------
__global__ __launch_bounds__(256) void scatter_kernel(const int* __restrict__ eidx,
                                                      const float4* __restrict__ ea,
                                                      const uchar* __restrict__ tag,
                                                      int* __restrict__ cursor,
                                                      int4* __restrict__ se4) {
    const int part = blockIdx.x & (NPART - 1);
    const int gb = blockIdx.x >> 3;
    const int tid = gb * 256 + threadIdx.x;
    const int stride = (gridDim.x >> 3) * 256;
    for (int e = tid; e < NE; e += stride) {
        if ((int)tag[e] != part) continue;
        int dst = eidx[NE + e];
        int src = eidx[e];
        float4 a = ea[e];
        int4 p;
        p.x = src;
        p.y = (int)(f2bf(a.x) | (f2bf(a.y) << 16));
        p.z = (int)(f2bf(a.z) | (f2bf(a.w) << 16));
        p.w = 0;
        int pos = atomicAdd(&cursor[dst], 1);
        se4[pos] = p;
    }
}

// ---------- Layer 1 aggregation only: z1[n][0..6] = x + sum relu(...), z1[n][7]=0 ----------
__global__ __launch_bounds__(256) void aggr1_kernel(
    const float* __restrict__ x, const int4* __restrict__ se4,
    const int* __restrict__ offs,
    const float* __restrict__ We1, const float* __restrict__ be1,
    float* __restrict__ z1)
{
    __shared__ float sWe[32];
    __shared__ float sbe[8];
    int tid = threadIdx.x;
    if (tid < 32) { int k = tid >> 3, dd = tid & 7; sWe[tid] = (dd < 7) ? We1[k * 7 + dd] : 0.f; }
    if (tid < 8)  sbe[tid] = (tid < 7) ? be1[tid] : 0.f;
    __syncthreads();

    const int w = tid >> 6, lane = tid & 63;
    const int jg = lane >> 3, d = lane & 7;

    for (int n = blockIdx.x * 4 + w; n < NN; n += gridDim.x * 4) {
        const int off = offs[n];
        const int deg = offs[n + 1] - off;
        float acc = 0.f;
        for (int j0 = 0; j0 < deg; j0 += 16) {
            int ja = j0 + jg;
            int jb = j0 + 8 + jg;
            int4 pa = se4[off + ((ja < deg) ? ja : 0)];
            int4 pb = se4[off + ((jb < deg) ? jb : 0)];
            float xa = (d < 7) ? x[(size_t)pa.x * 7 + d] : 0.f;
            float xb = (d < 7) ? x[(size_t)pb.x * 7 + d] : 0.f;
            float va = sbe[d] + bf2f_lo((uint)pa.y) * sWe[d] + bf2f_hi((uint)pa.y) * sWe[8 + d]
                     + bf2f_lo((uint)pa.z) * sWe[16 + d] + bf2f_hi((uint)pa.z) * sWe[24 + d] + xa;
            float vb = sbe[d] + bf2f_lo((uint)pb.y) * sWe[d] + bf2f_hi((uint)pb.y) * sWe[8 + d]
                     + bf2f_lo((uint)pb.z) * sWe[16 + d] + bf2f_hi((uint)pb.z) * sWe[24 + d] + xb;
            va = (d < 7 && ja < deg) ? fmaxf(va, 0.f) : 0.f;
            vb = (d < 7 && jb < deg) ? fmaxf(vb, 0.f) : 0.f;
            acc += va + vb;
        }
        acc += __shfl_xor(acc, 8);
        acc += __shfl_xor(acc, 16);
        acc += __shfl_xor(acc, 32);
        if (jg == 0)
            z1[(size_t)n * 8 + d] = (d < 7) ? (x[(size_t)n * 7 + d] + acc) : 0.f;
    }
}

// ---------- node-1 MLP via MFMA: h1 = relu(relu(z1@W1a+b1a)@W1b+b1b) ----------
// 64 nodes/block. A[m=lane&15][k=quad*8+j]; C/D: col=lane&15, row=quad*4+r (validated R9)
__global__ __launch_bounds__(256) void node1_kernel(
    const float* __restrict__ z1,
    const float* __restrict__ W1a, const float* __restrict__ b1a,
    const float* __restrict__ W1b, const float* __restrict__ b1b,
    uint* __restrict__ h1u)
{
    __shared__ __align__(16) ushort sT[64 * MSTRIDE];
    __shared__ __align__(16) ushort sO[64 * 64];
    const int t = threadIdx.x;
    const int w = t >> 6, lane = t & 63;
    const int qm = lane & 15, quad = lane >> 4;
    const int n0 = blockIdx.x * 64;
    const int node = n0 + w * 16 + qm;

    // register B-frags
    short8 wa1 = (short8)0;               // GEMM1, K=8 live in quad 0 only
    if (quad == 0) {
        #pragma unroll
        for (int j = 0; j < 7; ++j) { /* per nt below */ }
    }
    short8 wa1n[4];
    #pragma unroll
    for (int nt = 0; nt < 4; ++nt) {
        short8 v = (short8)0;
        if (quad == 0) {
            #pragma unroll
            for (int j = 0; j < 7; ++j)
                v[j] = (short)f2bf(W1a[j * 64 + nt * 16 + qm]);
        }
        wa1n[nt] = v;
    }
    short8 wb1[2][4];
    #pragma unroll
    for (int s = 0; s < 2; ++s)
        #pragma unroll
        for (int nt = 0; nt < 4; ++nt) {
            short8 v;
            #pragma unroll
            for (int j = 0; j < 8; ++j)
                v[j] = (short)f2bf(W1b[(s * 32 + quad * 8 + j) * 64 + nt * 16 + qm]);
            wb1[s][nt] = v;
        }
    float ba[4], bb[4];
    #pragma unroll
    for (int nt = 0; nt < 4; ++nt) { ba[nt] = b1a[nt * 16 + qm]; bb[nt] = b1b[nt * 16 + qm]; }

    // A-frag GEMM1: quad 0 holds z1 row (k=0..7), others zero
    short8 af1 = (short8)0;
    if (quad == 0 && node < NN) {
        const float4 za = *(const float4*)(z1 + (size_t)node * 8);
        const float4 zbv = *(const float4*)(z1 + (size_t)node * 8 + 4);
        af1[0] = (short)f2bf(za.x); af1[1] = (short)f2bf(za.y);
        af1[2] = (short)f2bf(za.z); af1[3] = (short)f2bf(za.w);
        af1[4] = (short)f2bf(zbv.x); af1[5] = (short)f2bf(zbv.y);
        af1[6] = (short)f2bf(zbv.z); af1[7] = (short)f2bf(zbv.w);
    }
    float4v acc[4];
    #pragma unroll
    for (int nt = 0; nt < 4; ++nt) {
        acc[nt] = (float4v){0.f, 0.f, 0.f, 0.f};
        acc[nt] = __builtin_amdgcn_mfma_f32_16x16x32_bf16(af1, wa1n[nt], acc[nt], 0, 0, 0);
    }
    #pragma unroll
    for (int nt = 0; nt < 4; ++nt)
        #pragma unroll
        for (int r = 0; r < 4; ++r)
            sT[(w * 16 + quad * 4 + r) * MSTRIDE + nt * 16 + qm] =
                (ushort)f2bf(fmaxf(acc[nt][r] + ba[nt], 0.f));
    __syncthreads();

    // GEMM2
    #pragma unroll
    for (int nt = 0; nt < 4; ++nt) acc[nt] = (float4v){0.f, 0.f, 0.f, 0.f};
    #pragma unroll
    for (int s = 0; s < 2; ++s) {
        short8 af = *(const short8*)&sT[(w * 16 + qm) * MSTRIDE + s * 32 + quad * 8];
        #pragma unroll
        for (int nt = 0; nt < 4; ++nt)
            acc[nt] = __builtin_amdgcn_mfma_f32_16x16x32_bf16(af, wb1[s][nt], acc[nt], 0, 0, 0);
    }
    #pragma unroll
    for (int nt = 0; nt < 4; ++nt)
        #pragma unroll
        for (int r = 0; r < 4; ++r)
            sO[(w * 16 + quad * 4 + r) * 64 + nt * 16 + qm] =
                (ushort)f2bf(fmaxf(acc[nt][r] + bb[nt], 0.f));
    __syncthreads();
    // coalesced packed write
    for (int i = t; i < 64 * 32; i += 256) {
        int nd = i >> 5;
        if (n0 + nd < NN) h1u[(size_t)(n0 + nd) * 32 + (i & 31)] = ((const uint*)sO)[i];
    }
    (void)wa1;
}

// ---------- Layer 2 aggregation: 2 dims/lane, 16 edges (8 dword gathers) in flight ----------
__global__ __launch_bounds__(256) void aggr2_kernel(
    const uint* __restrict__ h1u, const int4* __restrict__ se4,
    const int* __restrict__ offs,
    const float* __restrict__ We2, const float* __restrict__ be2,
    uint* __restrict__ zb)
{
    __shared__ float sWe[256];
    __shared__ float sbe[64];
    int tid = threadIdx.x;
    sWe[tid] = We2[tid];
    if (tid < 64) sbe[tid] = be2[tid];
    __syncthreads();
    const int w = tid >> 6, lane = tid & 63;
    const int l = lane & 31;
    const int half8 = (lane >> 5) << 3;
    const int n = blockIdx.x * 4 + w;
    const int off = offs[n];
    const int deg = offs[n + 1] - off;
    const float w0x = sWe[2 * l],       w0y = sWe[2 * l + 1];
    const float w1x = sWe[64 + 2 * l],  w1y = sWe[64 + 2 * l + 1];
    const float w2x = sWe[128 + 2 * l], w2y = sWe[128 + 2 * l + 1];
    const float w3x = sWe[192 + 2 * l], w3y = sWe[192 + 2 * l + 1];
    const float bbx = sbe[2 * l],       bby = sbe[2 * l + 1];

    float accx = 0.f, accy = 0.f;
    for (int jb = 0; jb < deg; jb += 16) {
        int m = deg - jb;
        int ll = (lane < 16) ? ((lane < m) ? lane : 0) : 0;
        int4 p = se4[off + jb + ll];
        uint g[8];
        #pragma unroll
        for (int k = 0; k < 8; ++k) {
            int mk = k + half8;
            int sk = __shfl(p.x, (mk < m) ? mk : 0);
            g[k] = h1u[(size_t)sk * 32 + l];
        }
        #pragma unroll
        for (int k = 0; k < 8; ++k) {
            int mk = k + half8;
            int sl = (mk < m) ? mk : 0;
            uint py = (uint)__shfl(p.y, sl);
            uint pz = (uint)__shfl(p.z, sl);
            float e0 = bf2f_lo(py), e1 = bf2f_hi(py);
            float e2 = bf2f_lo(pz), e3 = bf2f_hi(pz);
            float bx = bbx + e0 * w0x + e1 * w1x + e2 * w2x + e3 * w3x;
            float by = bby + e0 * w0y + e1 * w1y + e2 * w2y + e3 * w3y;
            float tx = fmaxf(bf2f_lo(g[k]) + bx, 0.f);
            float ty = fmaxf(bf2f_hi(g[k]) + by, 0.f);
            if (mk < m) { accx += tx; accy += ty; }
        }
    }
    accx += __shfl_xor(accx, 32);
    accy += __shfl_xor(accy, 32);
    if (lane < 32) {
        uint sw = h1u[(size_t)n * 32 + l];
        float zx = bf2f_lo(sw) + accx;
        float zy = bf2f_hi(sw) + accy;
        zb[(size_t)n * 32 + l] = f2bf(zx) | (f2bf(zy) << 16);
    }
}

// ---------- Layer 2 MLP via MFMA + segmented-reduction pooling (batch is sorted) ----------
__global__ __launch_bounds__(256) void mlp2_kernel(
    const uint* __restrict__ zb,
    const float* __restrict__ W2a, const float* __restrict__ b2a,
    const float* __restrict__ W2b, const float* __restrict__ b2b,
    const int* __restrict__ batch,
    float* __restrict__ sums, float* __restrict__ cnt)
{
    __shared__ __align__(16) ushort sT[64 * MSTRIDE];
    __shared__ float sH[64 * 64];
    __shared__ int sB[64];
    __shared__ float pbuf[4][64];
    __shared__ int pcnt[4];
    const int t = threadIdx.x;
    const int w = t >> 6, lane = t & 63;
    const int qm = lane & 15, quad = lane >> 4;
    const int n0 = blockIdx.x * 64;
    const int node = n0 + w * 16 + qm;
    const int nv = (NN - n0 < 64) ? (NN - n0) : 64;

    if (t < 64) sB[t] = (n0 + t < NN) ? batch[n0 + t] : -2;

    // register B-frags for both GEMMs
    short8 wa[2][4], wb[2][4];
    #pragma unroll
    for (int s = 0; s < 2; ++s)
        #pragma unroll
        for (int nt = 0; nt < 4; ++nt) {
            short8 va, vb;
            #pragma unroll
            for (int j = 0; j < 8; ++j) {
                int k = s * 32 + quad * 8 + j, n = nt * 16 + qm;
                va[j] = (short)f2bf(W2a[k * 64 + n]);
                vb[j] = (short)f2bf(W2b[k * 64 + n]);
            }
            wa[s][nt] = va; wb[s][nt] = vb;
        }
    float ba[4], bb[4];
    #pragma unroll
    for (int nt = 0; nt < 4; ++nt) { ba[nt] = b2a[nt * 16 + qm]; bb[nt] = b2b[nt * 16 + qm]; }

    // GEMM1: A直接 from global zb (16B/lane, dense)
    float4v acc[4];
    #pragma unroll
    for (int nt = 0; nt < 4; ++nt) acc[nt] = (float4v){0.f, 0.f, 0.f, 0.f};
    #pragma unroll
    for (int s = 0; s < 2; ++s) {
        uint4 zw = (node < NN) ? *(const uint4*)&zb[(size_t)node * 32 + s * 16 + quad * 4]
                               : make_uint4(0, 0, 0, 0);
        short8 af;
        *(uint4*)&af = zw;
        #pragma unroll
        for (int nt = 0; nt < 4; ++nt)
            acc[nt] = __builtin_amdgcn_mfma_f32_16x16x32_bf16(af, wa[s][nt], acc[nt], 0, 0, 0);
    }
    #pragma unroll
    for (int nt = 0; nt < 4; ++nt)
        #pragma unroll
        for (int r = 0; r < 4; ++r)
            sT[(w * 16 + quad * 4 + r) * MSTRIDE + nt * 16 + qm] =
                (ushort)f2bf(fmaxf(acc[nt][r] + ba[nt], 0.f));
    __syncthreads();

    // GEMM2
    #pragma unroll
    for (int nt = 0; nt < 4; ++nt) acc[nt] = (float4v){0.f, 0.f, 0.f, 0.f};
    #pragma unroll
    for (int s = 0; s < 2; ++s) {
        short8 af = *(const short8*)&sT[(w * 16 + qm) * MSTRIDE + s * 32 + quad * 8];
        #pragma unroll
        for (int nt = 0; nt < 4; ++nt)
            acc[nt] = __builtin_amdgcn_mfma_f32_16x16x32_bf16(af, wb[s][nt], acc[nt], 0, 0, 0);
    }
    #pragma unroll
    for (int nt = 0; nt < 4; ++nt)
        #pragma unroll
        for (int r = 0; r < 4; ++r)
            sH[(w * 16 + quad * 4 + r) * 64 + nt * 16 + qm] = fmaxf(acc[nt][r] + bb[nt], 0.f);
    __syncthreads();

    // segmented pooling: block spans graphs [glo, ghi] (~2-3 typical)
    const int glo = sB[0];
    const int ghi = sB[nv - 1];
    const int c = t >> 6, d = t & 63;
    for (int g = glo; g <= ghi; ++g) {
        float p = 0.f;
        int lc = 0;
        #pragma unroll 4
        for (int i = 0; i < 16; ++i) {
            int nd = c * 16 + i;
            if (sB[nd] == g) { p += sH[nd * 64 + d]; ++lc; }
        }
        pbuf[c][d] = p;
        if (d == 0) pcnt[c] = lc;
        __syncthreads();
        int tc = pcnt[0] + pcnt[1] + pcnt[2] + pcnt[3];
        if (tc > 0) {
            if (c == 0) {
                float tot = pbuf[0][d] + pbuf[1][d] + pbuf[2][d] + pbuf[3][d];
                atomicAdd(&sums[(size_t)g * 64 + d], tot);
            }
            if (t == 0) atomicAdd(&cnt[g], (float)tc);
        }
        __syncthreads();
    }
}

// ---------- FC ----------
__global__ __launch_bounds__(256) void fc_kernel(
    const float* __restrict__ sums, const float* __restrict__ cnt,
    const float* __restrict__ Wfc, const float* __restrict__ bfc,
    float* __restrict__ out)
{
    int gid = blockIdx.x * blockDim.x + threadIdx.x;
    if (gid >= NG * 12) return;
    int g = gid / 12, jj = gid - g * 12;
    float inv = 1.f / fmaxf(cnt[g], 1.f);
    float acc = bfc[jj];
    #pragma unroll 8
    for (int k = 0; k < 64; ++k) acc += sums[(size_t)g * 64 + k] * inv * Wfc[k * 12 + jj];
    out[gid] = acc;
}

extern "C" void kernel_launch(void* const* d_in, const int* in_sizes, int n_in,
                              void* d_out, int out_size, void* d_ws, size_t ws_size,
                              hipStream_t stream)
{
    (void)in_sizes; (void)n_in; (void)out_size; (void)ws_size;
    const float*  x    = (const float*)d_in[0];
    const float4* ea   = (const float4*)d_in[1];
    const int*    eidx = (const int*)d_in[2];
    const int*    batch= (const int*)d_in[3];
    const float*  We1  = (const float*)d_in[4];
    const float*  be1  = (const float*)d_in[5];
    const float*  W1a  = (const float*)d_in[6];
    const float*  b1a  = (const float*)d_in[7];
    const float*  W1b  = (const float*)d_in[8];
    const float*  b1b  = (const float*)d_in[9];
    const float*  We2  = (const float*)d_in[10];
    const float*  be2  = (const float*)d_in[11];
    const float*  W2a  = (const float*)d_in[12];
    const float*  b2a  = (const float*)d_in[13];
    const float*  W2b  = (const float*)d_in[14];
    const float*  b2b  = (const float*)d_in[15];
    const float*  Wfc  = (const float*)d_in[16];
    const float*  bfc  = (const float*)d_in[17];
    float* out = (float*)d_out;
    float* ws  = (float*)d_ws;

    int*   deg    = (int*)(ws + OFF_DEG);
    float* sums   = ws + OFF_SUMS;
    float* cnt    = ws + OFF_CNT;
    int*   offs   = (int*)(ws + OFF_OFFS);
    int*   cursor = (int*)(ws + OFF_CURS);
    int*   btot   = (int*)(ws + OFF_BTOT);
    int*   bexcl  = (int*)(ws + OFF_BEXCL);
    uchar* tag    = (uchar*)(ws + OFF_TAG);
    int4*  se4    = (int4*)(ws + OFF_SE4);
    float* z1     = ws + OFF_Z1;
    uint*  h1u    = (uint*)(ws + OFF_H1);
    uint*  zb     = (uint*)(ws + OFF_Z);

    hipMemsetAsync(d_ws, 0, (size_t)ZERO_UNITS * 4, stream);

    hist_kernel   <<<1024, 256, 0, stream>>>(eidx, deg, tag);
    scanA_kernel  <<<NBLK, 256, 0, stream>>>(deg, offs, btot);
    scanB_kernel  <<<1,    256, 0, stream>>>(btot, bexcl);
    scanC_kernel  <<<NBLK, 256, 0, stream>>>(offs, bexcl, cursor);
    scatter_kernel<<<2048, 256, 0, stream>>>(eidx, ea, tag, cursor, se4);
    aggr1_kernel  <<<2500, 256, 0, stream>>>(x, se4, offs, We1, be1, z1);
    node1_kernel  <<<(NN + 63) / 64, 256, 0, stream>>>(z1, W1a, b1a, W1b, b1b, h1u);
    aggr2_kernel  <<<12500, 256, 0, stream>>>(h1u, se4, offs, We2, be2, zb);
    mlp2_kernel   <<<(NN + 63) / 64, 256, 0, stream>>>(zb, W2a, b2a, W2b, b2b, batch, sums, cnt);
    fc_kernel     <<<(NG * 12 + 255) / 256, 256, 0, stream>>>(sums, cnt, Wfc, bfc, out);
}

// Round 11
// 352.607 us; speedup vs baseline: 1.2678x; 1.0770x over previous
//
#include <hip/hip_runtime.h>

typedef unsigned char uchar;
typedef unsigned short ushort;
typedef unsigned int uint;

constexpr int NN = 50000;
constexpr int NE = 1600000;
constexpr int NG = 1000;
constexpr int NBLK = 196;            // scan blocks: 196*256 = 50176 >= NN
constexpr int NB2 = 196;             // coarse buckets of 256 dst nodes
constexpr int TILE = 4096;           // bin_kernel tile (edges per block)
constexpr int NTILE = (NE + TILE - 1) / TILE;   // 391
constexpr int SPAN_CAP = 9216;       // bucket span cap (mean 8192, sigma~90; +11 sigma)
constexpr int MSTRIDE = 72;          // bf16 LDS row stride (64 + 8 pad)

// workspace layout in 4-byte units
constexpr int OFF_DEG   = 0;          // int[50176]  (zeroed)
constexpr int OFF_SUMS  = 50176;      // f32[64000]  (zeroed)
constexpr int OFF_CNT   = 114176;     // f32[1024]   (zeroed)
constexpr int ZERO_UNITS= 115200;
constexpr int OFF_OFFS  = 115200;     // int[50176]
constexpr int OFF_BTOT  = 165376;     // int[256]
constexpr int OFF_BEXCL = 165632;     // int[256]
constexpr int OFF_BCUR  = 165888;     // int[256] bucket cursors (init in scanC)
constexpr int OFF_P0    = 166144;     // uint[NE]  src | dstloc<<16
constexpr int OFF_P1    = 1766144;    // uint[NE]  ea01 bf16x2
constexpr int OFF_P2    = 3366144;    // uint[NE]  ea23 bf16x2
constexpr int OFF_Z1    = 4966144;    // f32[NN*8]
constexpr int OFF_H1    = 5366144;    // uint[NN*32] packed bf16 h1
constexpr int OFF_Z     = 6966144;    // uint[NN*32] packed bf16 z
// end = 8,566,144 units = 34.3 MB

typedef __attribute__((ext_vector_type(8))) short short8;
typedef __attribute__((ext_vector_type(4))) float float4v;

__device__ __forceinline__ uint f2bf(float f) {
    uint u = __float_as_uint(f);
    return (u + 0x7fffu + ((u >> 16) & 1u)) >> 16;
}
__device__ __forceinline__ float bf2f_lo(uint p) { return __uint_as_float(p << 16); }
__device__ __forceinline__ float bf2f_hi(uint p) { return __uint_as_float(p & 0xffff0000u); }

// ---------- degree histogram ----------
__global__ __launch_bounds__(256) void hist_kernel(const int* __restrict__ eidx,
                                                   int* __restrict__ deg) {
    int tid = blockIdx.x * 256 + threadIdx.x;
    int stride = gridDim.x * 256;
    for (int e = tid; e < NE; e += stride) atomicAdd(&deg[eidx[NE + e]], 1);
}

__global__ __launch_bounds__(256) void scanA_kernel(const int* __restrict__ deg,
                                                    int* __restrict__ offs,
                                                    int* __restrict__ btot) {
    __shared__ int s[256];
    int t = threadIdx.x;
    int i = blockIdx.x * 256 + t;
    int v = (i < NN) ? deg[i] : 0;
    s[t] = v; __syncthreads();
    for (int o = 1; o < 256; o <<= 1) {
        int u = (t >= o) ? s[t - o] : 0;
        __syncthreads();
        s[t] += u;
        __syncthreads();
    }
    offs[i] = s[t] - v;
    if (t == 255) btot[blockIdx.x] = s[255];
}

__global__ __launch_bounds__(256) void scanB_kernel(const int* __restrict__ btot,
                                                    int* __restrict__ bexcl) {
    __shared__ int s[256];
    int t = threadIdx.x;
    int v = (t < NBLK) ? btot[t] : 0;
    s[t] = v; __syncthreads();
    for (int o = 1; o < 256; o <<= 1) {
        int u = (t >= o) ? s[t - o] : 0;
        __syncthreads();
        s[t] += u;
        __syncthreads();
    }
    bexcl[t] = s[t] - v;
}

__global__ __launch_bounds__(256) void scanC_kernel(int* __restrict__ offs,
                                                    const int* __restrict__ bexcl,
                                                    int* __restrict__ bcur) {
    int i = blockIdx.x * 256 + threadIdx.x;
    int o = offs[i] + bexcl[blockIdx.x];
    offs[i] = o;
    if (i < NN && (i & 255) == 0) bcur[i >> 8] = o;   // bucket write cursor = bucket base
}

// ---------- phase 1: bin edges into 196 coarse buckets with near-coalesced writes ----------
__global__ __launch_bounds__(256) void bin_kernel(const int* __restrict__ eidx,
                                                  const float4* __restrict__ ea,
                                                  int* __restrict__ bcur,
                                                  uint* __restrict__ p0,
                                                  uint* __restrict__ p1,
                                                  uint* __restrict__ p2) {
    __shared__ uint s0[TILE], s1[TILE], s2[TILE];
    __shared__ int hcnt[NB2], hoff[NB2 + 1], hcur[NB2], gbase[NB2];
    const int t = threadIdx.x;
    const int e0 = blockIdx.x * TILE;
    const int cnt = (NE - e0 < TILE) ? (NE - e0) : TILE;
    for (int i = t; i < NB2; i += 256) hcnt[i] = 0;
    __syncthreads();
    int dsts[16];
    #pragma unroll
    for (int k = 0; k < 16; ++k) {
        int i = t + k * 256;
        int d = (i < cnt) ? eidx[NE + e0 + i] : -1;
        dsts[k] = d;
        if (d >= 0) atomicAdd(&hcnt[d >> 8], 1);
    }
    __syncthreads();
    if (t == 0) {
        int a = 0;
        for (int b = 0; b < NB2; ++b) { hoff[b] = a; a += hcnt[b]; }
        hoff[NB2] = a;
    }
    __syncthreads();
    if (t < NB2) { hcur[t] = hoff[t]; gbase[t] = atomicAdd(&bcur[t], hcnt[t]); }
    __syncthreads();
    #pragma unroll
    for (int k = 0; k < 16; ++k) {
        int d = dsts[k];
        if (d < 0) continue;
        int i = t + k * 256;
        int e = e0 + i;
        int src = eidx[e];
        float4 a = ea[e];
        int lp = atomicAdd(&hcur[d >> 8], 1);
        s0[lp] = (uint)src | ((uint)(d & 255) << 16);
        s1[lp] = f2bf(a.x) | (f2bf(a.y) << 16);
        s2[lp] = f2bf(a.z) | (f2bf(a.w) << 16);
    }
    __syncthreads();
    for (int i = t; i < cnt; i += 256) {            // bucket-contiguous -> near-full-line writes
        int lo = 0, hi = NB2 - 1;
        while (lo < hi) { int mid = (lo + hi + 1) >> 1; if (hoff[mid] <= i) lo = mid; else hi = mid - 1; }
        int gp = gbase[lo] + (i - hoff[lo]);
        p0[gp] = s0[i]; p1[gp] = s1[i]; p2[gp] = s2[i];
    }
}

// ---------- phase 2: per-bucket in-place permute into exact CSR order (coalesced R/W) ----------
__global__ __launch_bounds__(256) void build_kernel(const int* __restrict__ offs,
                                                    uint* __restrict__ p0,
                                                    uint* __restrict__ p1,
                                                    uint* __restrict__ p2) {
    __shared__ uint s0[SPAN_CAP], s1[SPAN_CAP], s2[SPAN_CAP];
    __shared__ int lcur[256];
    const int t = threadIdx.x;
    const int b = blockIdx.x;
    const int nlo = b << 8;
    const int base = offs[nlo];
    int span = ((nlo + 256 <= NN) ? offs[nlo + 256] : NE) - base;
    if (span > SPAN_CAP) span = SPAN_CAP;           // statistically impossible; guards LDS
    lcur[t] = ((nlo + t < NN) ? offs[nlo + t] : NE) - base;
    __syncthreads();
    for (int i = t; i < span; i += 256) {
        uint r0 = p0[base + i], r1 = p1[base + i], r2 = p2[base + i];
        int dl = (int)((r0 >> 16) & 0xFFu);
        int pos = atomicAdd(&lcur[dl], 1);          // LDS atomic: cheap
        s0[pos] = r0; s1[pos] = r1; s2[pos] = r2;
    }
    __syncthreads();
    for (int i = t; i < span; i += 256) {           // fully coalesced writeback
        p0[base + i] = s0[i]; p1[base + i] = s1[i]; p2[base + i] = s2[i];
    }
}

// ---------- Layer 1 aggregation: z1[n][0..6] = x + sum relu(...), z1[n][7]=0 ----------
__global__ __launch_bounds__(256) void aggr1_kernel(
    const float* __restrict__ x,
    const uint* __restrict__ p0, const uint* __restrict__ p1, const uint* __restrict__ p2,
    const int* __restrict__ offs,
    const float* __restrict__ We1, const float* __restrict__ be1,
    float* __restrict__ z1)
{
    __shared__ float sWe[32];
    __shared__ float sbe[8];
    int tid = threadIdx.x;
    if (tid < 32) { int k = tid >> 3, dd = tid & 7; sWe[tid] = (dd < 7) ? We1[k * 7 + dd] : 0.f; }
    if (tid < 8)  sbe[tid] = (tid < 7) ? be1[tid] : 0.f;
    __syncthreads();

    const int w = tid >> 6, lane = tid & 63;
    const int jg = lane >> 3, d = lane & 7;

    for (int n = blockIdx.x * 4 + w; n < NN; n += gridDim.x * 4) {
        const int off = offs[n];
        const int deg = offs[n + 1] - off;
        float acc = 0.f;
        for (int j0 = 0; j0 < deg; j0 += 16) {
            int ja = j0 + jg;
            int jb = j0 + 8 + jg;
            int ia = off + ((ja < deg) ? ja : 0);
            int ib = off + ((jb < deg) ? jb : 0);
            uint r0a = p0[ia], r1a = p1[ia], r2a = p2[ia];
            uint r0b = p0[ib], r1b = p1[ib], r2b = p2[ib];
            float xa = (d < 7) ? x[(size_t)(r0a & 0xFFFFu) * 7 + d] : 0.f;
            float xb = (d < 7) ? x[(size_t)(r0b & 0xFFFFu) * 7 + d] : 0.f;
            float va = sbe[d] + bf2f_lo(r1a) * sWe[d] + bf2f_hi(r1a) * sWe[8 + d]
                     + bf2f_lo(r2a) * sWe[16 + d] + bf2f_hi(r2a) * sWe[24 + d] + xa;
            float vb = sbe[d] + bf2f_lo(r1b) * sWe[d] + bf2f_hi(r1b) * sWe[8 + d]
                     + bf2f_lo(r2b) * sWe[16 + d] + bf2f_hi(r2b) * sWe[24 + d] + xb;
            va = (d < 7 && ja < deg) ? fmaxf(va, 0.f) : 0.f;
            vb = (d < 7 && jb < deg) ? fmaxf(vb, 0.f) : 0.f;
            acc += va + vb;
        }
        acc += __shfl_xor(acc, 8);
        acc += __shfl_xor(acc, 16);
        acc += __shfl_xor(acc, 32);
        if (jg == 0)
            z1[(size_t)n * 8 + d] = (d < 7) ? (x[(size_t)n * 7 + d] + acc) : 0.f;
    }
}

// ---------- node-1 MLP via MFMA ----------
__global__ __launch_bounds__(256) void node1_kernel(
    const float* __restrict__ z1,
    const float* __restrict__ W1a, const float* __restrict__ b1a,
    const float* __restrict__ W1b, const float* __restrict__ b1b,
    uint* __restrict__ h1u)
{
    __shared__ __align__(16) ushort sT[64 * MSTRIDE];
    __shared__ __align__(16) ushort sO[64 * 64];
    const int t = threadIdx.x;
    const int w = t >> 6, lane = t & 63;
    const int qm = lane & 15, quad = lane >> 4;
    const int n0 = blockIdx.x * 64;
    const int node = n0 + w * 16 + qm;

    short8 wa1n[4];
    #pragma unroll
    for (int nt = 0; nt < 4; ++nt) {
        short8 v = (short8)0;
        if (quad == 0) {
            #pragma unroll
            for (int j = 0; j < 7; ++j)
                v[j] = (short)f2bf(W1a[j * 64 + nt * 16 + qm]);
        }
        wa1n[nt] = v;
    }
    short8 wb1[2][4];
    #pragma unroll
    for (int s = 0; s < 2; ++s)
        #pragma unroll
        for (int nt = 0; nt < 4; ++nt) {
            short8 v;
            #pragma unroll
            for (int j = 0; j < 8; ++j)
                v[j] = (short)f2bf(W1b[(s * 32 + quad * 8 + j) * 64 + nt * 16 + qm]);
            wb1[s][nt] = v;
        }
    float ba[4], bb[4];
    #pragma unroll
    for (int nt = 0; nt < 4; ++nt) { ba[nt] = b1a[nt * 16 + qm]; bb[nt] = b1b[nt * 16 + qm]; }

    short8 af1 = (short8)0;
    if (quad == 0 && node < NN) {
        const float4 za = *(const float4*)(z1 + (size_t)node * 8);
        const float4 zbv = *(const float4*)(z1 + (size_t)node * 8 + 4);
        af1[0] = (short)f2bf(za.x); af1[1] = (short)f2bf(za.y);
        af1[2] = (short)f2bf(za.z); af1[3] = (short)f2bf(za.w);
        af1[4] = (short)f2bf(zbv.x); af1[5] = (short)f2bf(zbv.y);
        af1[6] = (short)f2bf(zbv.z); af1[7] = (short)f2bf(zbv.w);
    }
    float4v acc[4];
    #pragma unroll
    for (int nt = 0; nt < 4; ++nt) {
        acc[nt] = (float4v){0.f, 0.f, 0.f, 0.f};
        acc[nt] = __builtin_amdgcn_mfma_f32_16x16x32_bf16(af1, wa1n[nt], acc[nt], 0, 0, 0);
    }
    #pragma unroll
    for (int nt = 0; nt < 4; ++nt)
        #pragma unroll
        for (int r = 0; r < 4; ++r)
            sT[(w * 16 + quad * 4 + r) * MSTRIDE + nt * 16 + qm] =
                (ushort)f2bf(fmaxf(acc[nt][r] + ba[nt], 0.f));
    __syncthreads();

    #pragma unroll
    for (int nt = 0; nt < 4; ++nt) acc[nt] = (float4v){0.f, 0.f, 0.f, 0.f};
    #pragma unroll
    for (int s = 0; s < 2; ++s) {
        short8 af = *(const short8*)&sT[(w * 16 + qm) * MSTRIDE + s * 32 + quad * 8];
        #pragma unroll
        for (int nt = 0; nt < 4; ++nt)
            acc[nt] = __builtin_amdgcn_mfma_f32_16x16x32_bf16(af, wb1[s][nt], acc[nt], 0, 0, 0);
    }
    #pragma unroll
    for (int nt = 0; nt < 4; ++nt)
        #pragma unroll
        for (int r = 0; r < 4; ++r)
            sO[(w * 16 + quad * 4 + r) * 64 + nt * 16 + qm] =
                (ushort)f2bf(fmaxf(acc[nt][r] + bb[nt], 0.f));
    __syncthreads();
    for (int i = t; i < 64 * 32; i += 256) {
        int nd = i >> 5;
        if (n0 + nd < NN) h1u[(size_t)(n0 + nd) * 32 + (i & 31)] = ((const uint*)sO)[i];
    }
}

// ---------- Layer 2 aggregation: 2 dims/lane, 16 edges (8 dword gathers) in flight ----------
__global__ __launch_bounds__(256) void aggr2_kernel(
    const uint* __restrict__ h1u,
    const uint* __restrict__ p0, const uint* __restrict__ p1, const uint* __restrict__ p2,
    const int* __restrict__ offs,
    const float* __restrict__ We2, const float* __restrict__ be2,
    uint* __restrict__ zb)
{
    __shared__ float sWe[256];
    __shared__ float sbe[64];
    int tid = threadIdx.x;
    sWe[tid] = We2[tid];
    if (tid < 64) sbe[tid] = be2[tid];
    __syncthreads();
    const int w = tid >> 6, lane = tid & 63;
    const int l = lane & 31;
    const int half8 = (lane >> 5) << 3;
    const int n = blockIdx.x * 4 + w;
    const int off = offs[n];
    const int deg = offs[n + 1] - off;
    const float w0x = sWe[2 * l],       w0y = sWe[2 * l + 1];
    const float w1x = sWe[64 + 2 * l],  w1y = sWe[64 + 2 * l + 1];
    const float w2x = sWe[128 + 2 * l], w2y = sWe[128 + 2 * l + 1];
    const float w3x = sWe[192 + 2 * l], w3y = sWe[192 + 2 * l + 1];
    const float bbx = sbe[2 * l],       bby = sbe[2 * l + 1];

    float accx = 0.f, accy = 0.f;
    for (int jb = 0; jb < deg; jb += 16) {
        int m = deg - jb;
        int ll = (lane < 16) ? ((lane < m) ? lane : 0) : 0;
        int idx = off + jb + ll;
        int sx = (int)(p0[idx] & 0xFFFFu);          // lanes 0..15: 16 edges
        uint e01 = p1[idx];
        uint e23 = p2[idx];
        uint g[8];
        #pragma unroll
        for (int k = 0; k < 8; ++k) {
            int mk = k + half8;
            int sk = __shfl(sx, (mk < m) ? mk : 0);
            g[k] = h1u[(size_t)sk * 32 + l];
        }
        #pragma unroll
        for (int k = 0; k < 8; ++k) {
            int mk = k + half8;
            int sl = (mk < m) ? mk : 0;
            uint py = (uint)__shfl((int)e01, sl);
            uint pz = (uint)__shfl((int)e23, sl);
            float e0 = bf2f_lo(py), e1 = bf2f_hi(py);
            float e2 = bf2f_lo(pz), e3 = bf2f_hi(pz);
            float bx = bbx + e0 * w0x + e1 * w1x + e2 * w2x + e3 * w3x;
            float by = bby + e0 * w0y + e1 * w1y + e2 * w2y + e3 * w3y;
            float tx = fmaxf(bf2f_lo(g[k]) + bx, 0.f);
            float ty = fmaxf(bf2f_hi(g[k]) + by, 0.f);
            if (mk < m) { accx += tx; accy += ty; }
        }
    }
    accx += __shfl_xor(accx, 32);
    accy += __shfl_xor(accy, 32);
    if (lane < 32) {
        uint sw = h1u[(size_t)n * 32 + l];
        float zx = bf2f_lo(sw) + accx;
        float zy = bf2f_hi(sw) + accy;
        zb[(size_t)n * 32 + l] = f2bf(zx) | (f2bf(zy) << 16);
    }
}

// ---------- Layer 2 MLP via MFMA + segmented-reduction pooling ----------
__global__ __launch_bounds__(256) void mlp2_kernel(
    const uint* __restrict__ zb,
    const float* __restrict__ W2a, const float* __restrict__ b2a,
    const float* __restrict__ W2b, const float* __restrict__ b2b,
    const int* __restrict__ batch,
    float* __restrict__ sums, float* __restrict__ cnt)
{
    __shared__ __align__(16) ushort sT[64 * MSTRIDE];
    __shared__ float sH[64 * 64];
    __shared__ int sB[64];
    __shared__ float pbuf[4][64];
    __shared__ int pcnt[4];
    const int t = threadIdx.x;
    const int w = t >> 6, lane = t & 63;
    const int qm = lane & 15, quad = lane >> 4;
    const int n0 = blockIdx.x * 64;
    const int node = n0 + w * 16 + qm;
    const int nv = (NN - n0 < 64) ? (NN - n0) : 64;

    if (t < 64) sB[t] = (n0 + t < NN) ? batch[n0 + t] : -2;

    short8 wa[2][4], wb[2][4];
    #pragma unroll
    for (int s = 0; s < 2; ++s)
        #pragma unroll
        for (int nt = 0; nt < 4; ++nt) {
            short8 va, vb;
            #pragma unroll
            for (int j = 0; j < 8; ++j) {
                int k = s * 32 + quad * 8 + j, n = nt * 16 + qm;
                va[j] = (short)f2bf(W2a[k * 64 + n]);
                vb[j] = (short)f2bf(W2b[k * 64 + n]);
            }
            wa[s][nt] = va; wb[s][nt] = vb;
        }
    float ba[4], bb[4];
    #pragma unroll
    for (int nt = 0; nt < 4; ++nt) { ba[nt] = b2a[nt * 16 + qm]; bb[nt] = b2b[nt * 16 + qm]; }

    float4v acc[4];
    #pragma unroll
    for (int nt = 0; nt < 4; ++nt) acc[nt] = (float4v){0.f, 0.f, 0.f, 0.f};
    #pragma unroll
    for (int s = 0; s < 2; ++s) {
        uint4 zw = (node < NN) ? *(const uint4*)&zb[(size_t)node * 32 + s * 16 + quad * 4]
                               : make_uint4(0, 0, 0, 0);
        short8 af;
        *(uint4*)&af = zw;
        #pragma unroll
        for (int nt = 0; nt < 4; ++nt)
            acc[nt] = __builtin_amdgcn_mfma_f32_16x16x32_bf16(af, wa[s][nt], acc[nt], 0, 0, 0);
    }
    #pragma unroll
    for (int nt = 0; nt < 4; ++nt)
        #pragma unroll
        for (int r = 0; r < 4; ++r)
            sT[(w * 16 + quad * 4 + r) * MSTRIDE + nt * 16 + qm] =
                (ushort)f2bf(fmaxf(acc[nt][r] + ba[nt], 0.f));
    __syncthreads();

    #pragma unroll
    for (int nt = 0; nt < 4; ++nt) acc[nt] = (float4v){0.f, 0.f, 0.f, 0.f};
    #pragma unroll
    for (int s = 0; s < 2; ++s) {
        short8 af = *(const short8*)&sT[(w * 16 + qm) * MSTRIDE + s * 32 + quad * 8];
        #pragma unroll
        for (int nt = 0; nt < 4; ++nt)
            acc[nt] = __builtin_amdgcn_mfma_f32_16x16x32_bf16(af, wb[s][nt], acc[nt], 0, 0, 0);
    }
    #pragma unroll
    for (int nt = 0; nt < 4; ++nt)
        #pragma unroll
        for (int r = 0; r < 4; ++r)
            sH[(w * 16 + quad * 4 + r) * 64 + nt * 16 + qm] = fmaxf(acc[nt][r] + bb[nt], 0.f);
    __syncthreads();

    const int glo = sB[0];
    const int ghi = sB[nv - 1];
    const int c = t >> 6, d = t & 63;
    for (int g = glo; g <= ghi; ++g) {
        float p = 0.f;
        int lc = 0;
        #pragma unroll 4
        for (int i = 0; i < 16; ++i) {
            int nd = c * 16 + i;
            if (sB[nd] == g) { p += sH[nd * 64 + d]; ++lc; }
        }
        pbuf[c][d] = p;
        if (d == 0) pcnt[c] = lc;
        __syncthreads();
        int tc = pcnt[0] + pcnt[1] + pcnt[2] + pcnt[3];
        if (tc > 0) {
            if (c == 0) {
                float tot = pbuf[0][d] + pbuf[1][d] + pbuf[2][d] + pbuf[3][d];
                atomicAdd(&sums[(size_t)g * 64 + d], tot);
            }
            if (t == 0) atomicAdd(&cnt[g], (float)tc);
        }
        __syncthreads();
    }
}

// ---------- FC ----------
__global__ __launch_bounds__(256) void fc_kernel(
    const float* __restrict__ sums, const float* __restrict__ cnt,
    const float* __restrict__ Wfc, const float* __restrict__ bfc,
    float* __restrict__ out)
{
    int gid = blockIdx.x * blockDim.x + threadIdx.x;
    if (gid >= NG * 12) return;
    int g = gid / 12, jj = gid - g * 12;
    float inv = 1.f / fmaxf(cnt[g], 1.f);
    float acc = bfc[jj];
    #pragma unroll 8
    for (int k = 0; k < 64; ++k) acc += sums[(size_t)g * 64 + k] * inv * Wfc[k * 12 + jj];
    out[gid] = acc;
}

extern "C" void kernel_launch(void* const* d_in, const int* in_sizes, int n_in,
                              void* d_out, int out_size, void* d_ws, size_t ws_size,
                              hipStream_t stream)
{
    (void)in_sizes; (void)n_in; (void)out_size; (void)ws_size;
    const float*  x    = (const float*)d_in[0];
    const float4* ea   = (const float4*)d_in[1];
    const int*    eidx = (const int*)d_in[2];
    const int*    batch= (const int*)d_in[3];
    const float*  We1  = (const float*)d_in[4];
    const float*  be1  = (const float*)d_in[5];
    const float*  W1a  = (const float*)d_in[6];
    const float*  b1a  = (const float*)d_in[7];
    const float*  W1b  = (const float*)d_in[8];
    const float*  b1b  = (const float*)d_in[9];
    const float*  We2  = (const float*)d_in[10];
    const float*  be2  = (const float*)d_in[11];
    const float*  W2a  = (const float*)d_in[12];
    const float*  b2a  = (const float*)d_in[13];
    const float*  W2b  = (const float*)d_in[14];
    const float*  b2b  = (const float*)d_in[15];
    const float*  Wfc  = (const float*)d_in[16];
    const float*  bfc  = (const float*)d_in[17];
    float* out = (float*)d_out;
    float* ws  = (float*)d_ws;

    int*   deg   = (int*)(ws + OFF_DEG);
    float* sums  = ws + OFF_SUMS;
    float* cnt   = ws + OFF_CNT;
    int*   offs  = (int*)(ws + OFF_OFFS);
    int*   btot  = (int*)(ws + OFF_BTOT);
    int*   bexcl = (int*)(ws + OFF_BEXCL);
    int*   bcur  = (int*)(ws + OFF_BCUR);
    uint*  p0    = (uint*)(ws + OFF_P0);
    uint*  p1    = (uint*)(ws + OFF_P1);
    uint*  p2    = (uint*)(ws + OFF_P2);
    float* z1    = ws + OFF_Z1;
    uint*  h1u   = (uint*)(ws + OFF_H1);
    uint*  zb    = (uint*)(ws + OFF_Z);

    hipMemsetAsync(d_ws, 0, (size_t)ZERO_UNITS * 4, stream);

    hist_kernel <<<1024, 256, 0, stream>>>(eidx, deg);
    scanA_kernel<<<NBLK, 256, 0, stream>>>(deg, offs, btot);
    scanB_kernel<<<1,    256, 0, stream>>>(btot, bexcl);
    scanC_kernel<<<NBLK, 256, 0, stream>>>(offs, bexcl, bcur);
    bin_kernel  <<<NTILE, 256, 0, stream>>>(eidx, ea, bcur, p0, p1, p2);
    build_kernel<<<NB2, 256, 0, stream>>>(offs, p0, p1, p2);
    aggr1_kernel<<<2500, 256, 0, stream>>>(x, p0, p1, p2, offs, We1, be1, z1);
    node1_kernel<<<(NN + 63) / 64, 256, 0, stream>>>(z1, W1a, b1a, W1b, b1b, h1u);
    aggr2_kernel<<<12500, 256, 0, stream>>>(h1u, p0, p1, p2, offs, We2, be2, zb);
    mlp2_kernel <<<(NN + 63) / 64, 256, 0, stream>>>(zb, W2a, b2a, W2b, b2b, batch, sums, cnt);
    fc_kernel   <<<(NG * 12 + 255) / 256, 256, 0, stream>>>(sums, cnt, Wfc, bfc, out);
}

// Round 12
// 292.838 us; speedup vs baseline: 1.5265x; 1.2041x over previous
//
#include <hip/hip_runtime.h>

typedef unsigned char uchar;
typedef unsigned short ushort;
typedef unsigned int uint;

constexpr int NN = 50000;
constexpr int NE = 1600000;
constexpr int NG = 1000;
constexpr int NB2 = 196;             // coarse buckets of 256 dst nodes
constexpr int TILE = 4096;           // bin_kernel tile (edges per block)
constexpr int NTILE = (NE + TILE - 1) / TILE;   // 391
constexpr int SPAN_CAP = 9216;       // bucket span cap (mean 8163, +11 sigma)
constexpr int MSTRIDE = 72;          // bf16 LDS row stride (64 + 8 pad)

// workspace layout in 4-byte units
constexpr int OFF_BCNT  = 0;          // int[256]    (zeroed)
constexpr int OFF_SUMS  = 256;        // f32[64000]  (zeroed)
constexpr int OFF_CNT   = 64256;      // f32[1024]   (zeroed)
constexpr int ZERO_UNITS= 65280;
constexpr int OFF_BBASE = 65280;      // int[256]
constexpr int OFF_BCUR  = 65536;      // int[256]
constexpr int OFF_OFFS  = 65792;      // int[50176]
constexpr int OFF_P0    = 116224;     // uint[NE]  src | dstloc<<16
constexpr int OFF_P1    = 1716224;    // uint[NE]  ea01 bf16x2
constexpr int OFF_P2    = 3316224;    // uint[NE]  ea23 bf16x2
constexpr int OFF_Z1    = 4916224;    // f32[NN*8]  (16B-aligned)
constexpr int OFF_H1    = 5316224;    // uint[NN*32] packed bf16 h1
constexpr int OFF_Z     = 6916224;    // uint[NN*32] packed bf16 z (16B-aligned)
// end = 8,516,224 units = 34.1 MB

typedef __attribute__((ext_vector_type(8))) short short8;
typedef __attribute__((ext_vector_type(4))) float float4v;

__device__ __forceinline__ uint f2bf(float f) {
    uint u = __float_as_uint(f);
    return (u + 0x7fffu + ((u >> 16) & 1u)) >> 16;
}
__device__ __forceinline__ float bf2f_lo(uint p) { return __uint_as_float(p << 16); }
__device__ __forceinline__ float bf2f_hi(uint p) { return __uint_as_float(p & 0xffff0000u); }

// ---------- coarse-bucket histogram (LDS-privatized: ~50K bulk global atomics total) ----------
__global__ __launch_bounds__(256) void bhist_kernel(const int* __restrict__ eidx,
                                                    int* __restrict__ bcnt) {
    __shared__ int lh[NB2];
    for (int i = threadIdx.x; i < NB2; i += 256) lh[i] = 0;
    __syncthreads();
    int tid = blockIdx.x * 256 + threadIdx.x;
    int stride = gridDim.x * 256;
    for (int e = tid; e < NE; e += stride) atomicAdd(&lh[eidx[NE + e] >> 8], 1);
    __syncthreads();
    for (int i = threadIdx.x; i < NB2; i += 256) if (lh[i]) atomicAdd(&bcnt[i], lh[i]);
}

// ---------- bucket scan: bbase = exclusive prefix; bcur = write cursor ----------
__global__ __launch_bounds__(256) void bscan_kernel(const int* __restrict__ bcnt,
                                                    int* __restrict__ bbase,
                                                    int* __restrict__ bcur) {
    __shared__ int s[256];
    int t = threadIdx.x;
    int v = (t < NB2) ? bcnt[t] : 0;
    s[t] = v; __syncthreads();
    for (int o = 1; o < 256; o <<= 1) {
        int u = (t >= o) ? s[t - o] : 0;
        __syncthreads();
        s[t] += u;
        __syncthreads();
    }
    bbase[t] = s[t] - v;
    bcur[t] = s[t] - v;
}

// ---------- phase 1: bin edges into coarse buckets with near-coalesced writes ----------
__global__ __launch_bounds__(256) void bin_kernel(const int* __restrict__ eidx,
                                                  const float4* __restrict__ ea,
                                                  int* __restrict__ bcur,
                                                  uint* __restrict__ p0,
                                                  uint* __restrict__ p1,
                                                  uint* __restrict__ p2) {
    __shared__ uint s0[TILE], s1[TILE], s2[TILE];
    __shared__ int hcnt[NB2], hoff[NB2 + 1], hcur[NB2], gbase[NB2];
    const int t = threadIdx.x;
    const int e0 = blockIdx.x * TILE;
    const int cnt = (NE - e0 < TILE) ? (NE - e0) : TILE;
    for (int i = t; i < NB2; i += 256) hcnt[i] = 0;
    __syncthreads();
    int dsts[16];
    #pragma unroll
    for (int k = 0; k < 16; ++k) {
        int i = t + k * 256;
        int d = (i < cnt) ? eidx[NE + e0 + i] : -1;
        dsts[k] = d;
        if (d >= 0) atomicAdd(&hcnt[d >> 8], 1);
    }
    __syncthreads();
    if (t == 0) {
        int a = 0;
        for (int b = 0; b < NB2; ++b) { hoff[b] = a; a += hcnt[b]; }
        hoff[NB2] = a;
    }
    __syncthreads();
    if (t < NB2) { hcur[t] = hoff[t]; gbase[t] = atomicAdd(&bcur[t], hcnt[t]); }
    __syncthreads();
    #pragma unroll
    for (int k = 0; k < 16; ++k) {
        int d = dsts[k];
        if (d < 0) continue;
        int i = t + k * 256;
        int e = e0 + i;
        int src = eidx[e];
        float4 a = ea[e];
        int lp = atomicAdd(&hcur[d >> 8], 1);
        s0[lp] = (uint)src | ((uint)(d & 255) << 16);
        s1[lp] = f2bf(a.x) | (f2bf(a.y) << 16);
        s2[lp] = f2bf(a.z) | (f2bf(a.w) << 16);
    }
    __syncthreads();
    for (int i = t; i < cnt; i += 256) {            // bucket-contiguous -> near-full-line writes
        int lo = 0, hi = NB2 - 1;
        while (lo < hi) { int mid = (lo + hi + 1) >> 1; if (hoff[mid] <= i) lo = mid; else hi = mid - 1; }
        int gp = gbase[lo] + (i - hoff[lo]);
        p0[gp] = s0[i]; p1[gp] = s1[i]; p2[gp] = s2[i];
    }
}

// ---------- phase 2: per-bucket degree count + local scan + offs write + in-place permute ----------
__global__ __launch_bounds__(256) void build_kernel(const int* __restrict__ bbase,
                                                    const int* __restrict__ bcnt,
                                                    int* __restrict__ offs,
                                                    uint* __restrict__ p0,
                                                    uint* __restrict__ p1,
                                                    uint* __restrict__ p2) {
    __shared__ uint s0[SPAN_CAP], s1[SPAN_CAP], s2[SPAN_CAP];
    __shared__ int ldeg[256], lcur[256], sscan[256];
    const int t = threadIdx.x;
    const int b = blockIdx.x;
    const int nlo = b << 8;
    const int base = bbase[b];
    int span = bcnt[b];
    if (span > SPAN_CAP) span = SPAN_CAP;           // statistically impossible; guards LDS
    ldeg[t] = 0;
    __syncthreads();
    // pass 1: count local degrees (coalesced read; L2-hot for pass 2)
    for (int i = t; i < span; i += 256)
        atomicAdd(&ldeg[(p0[base + i] >> 16) & 0xFFu], 1);
    __syncthreads();
    // block scan over 256 local degrees
    int v = ldeg[t];
    sscan[t] = v; __syncthreads();
    for (int o = 1; o < 256; o <<= 1) {
        int u = (t >= o) ? sscan[t - o] : 0;
        __syncthreads();
        sscan[t] += u;
        __syncthreads();
    }
    int exc = sscan[t] - v;
    lcur[t] = exc;
    int gi = nlo + t;
    if (gi < NN) offs[gi] = base + exc;
    else if (gi < 50176) offs[gi] = NE;             // sentinel region incl. offs[NN]
    __syncthreads();
    // pass 2: place records into ordered LDS staging, then coalesced writeback
    for (int i = t; i < span; i += 256) {
        uint r0 = p0[base + i], r1 = p1[base + i], r2 = p2[base + i];
        int pos = atomicAdd(&lcur[(r0 >> 16) & 0xFFu], 1);
        s0[pos] = r0; s1[pos] = r1; s2[pos] = r2;
    }
    __syncthreads();
    for (int i = t; i < span; i += 256) {
        p0[base + i] = s0[i]; p1[base + i] = s1[i]; p2[base + i] = s2[i];
    }
}

// ---------- Layer 1 aggregation: z1[n][0..6] = x + sum relu(...), z1[n][7]=0 ----------
__global__ __launch_bounds__(256) void aggr1_kernel(
    const float* __restrict__ x,
    const uint* __restrict__ p0, const uint* __restrict__ p1, const uint* __restrict__ p2,
    const int* __restrict__ offs,
    const float* __restrict__ We1, const float* __restrict__ be1,
    float* __restrict__ z1)
{
    __shared__ float sWe[32];
    __shared__ float sbe[8];
    int tid = threadIdx.x;
    if (tid < 32) { int k = tid >> 3, dd = tid & 7; sWe[tid] = (dd < 7) ? We1[k * 7 + dd] : 0.f; }
    if (tid < 8)  sbe[tid] = (tid < 7) ? be1[tid] : 0.f;
    __syncthreads();

    const int w = tid >> 6, lane = tid & 63;
    const int jg = lane >> 3, d = lane & 7;

    for (int n = blockIdx.x * 4 + w; n < NN; n += gridDim.x * 4) {
        const int off = offs[n];
        const int deg = offs[n + 1] - off;
        float acc = 0.f;
        for (int j0 = 0; j0 < deg; j0 += 16) {
            int ja = j0 + jg;
            int jb = j0 + 8 + jg;
            int ia = off + ((ja < deg) ? ja : 0);
            int ib = off + ((jb < deg) ? jb : 0);
            uint r0a = p0[ia], r1a = p1[ia], r2a = p2[ia];
            uint r0b = p0[ib], r1b = p1[ib], r2b = p2[ib];
            float xa = (d < 7) ? x[(size_t)(r0a & 0xFFFFu) * 7 + d] : 0.f;
            float xb = (d < 7) ? x[(size_t)(r0b & 0xFFFFu) * 7 + d] : 0.f;
            float va = sbe[d] + bf2f_lo(r1a) * sWe[d] + bf2f_hi(r1a) * sWe[8 + d]
                     + bf2f_lo(r2a) * sWe[16 + d] + bf2f_hi(r2a) * sWe[24 + d] + xa;
            float vb = sbe[d] + bf2f_lo(r1b) * sWe[d] + bf2f_hi(r1b) * sWe[8 + d]
                     + bf2f_lo(r2b) * sWe[16 + d] + bf2f_hi(r2b) * sWe[24 + d] + xb;
            va = (d < 7 && ja < deg) ? fmaxf(va, 0.f) : 0.f;
            vb = (d < 7 && jb < deg) ? fmaxf(vb, 0.f) : 0.f;
            acc += va + vb;
        }
        acc += __shfl_xor(acc, 8);
        acc += __shfl_xor(acc, 16);
        acc += __shfl_xor(acc, 32);
        if (jg == 0)
            z1[(size_t)n * 8 + d] = (d < 7) ? (x[(size_t)n * 7 + d] + acc) : 0.f;
    }
}

// ---------- node-1 MLP via MFMA ----------
__global__ __launch_bounds__(256) void node1_kernel(
    const float* __restrict__ z1,
    const float* __restrict__ W1a, const float* __restrict__ b1a,
    const float* __restrict__ W1b, const float* __restrict__ b1b,
    uint* __restrict__ h1u)
{
    __shared__ __align__(16) ushort sT[64 * MSTRIDE];
    __shared__ __align__(16) ushort sO[64 * 64];
    const int t = threadIdx.x;
    const int w = t >> 6, lane = t & 63;
    const int qm = lane & 15, quad = lane >> 4;
    const int n0 = blockIdx.x * 64;
    const int node = n0 + w * 16 + qm;

    short8 wa1n[4];
    #pragma unroll
    for (int nt = 0; nt < 4; ++nt) {
        short8 v = (short8)0;
        if (quad == 0) {
            #pragma unroll
            for (int j = 0; j < 7; ++j)
                v[j] = (short)f2bf(W1a[j * 64 + nt * 16 + qm]);
        }
        wa1n[nt] = v;
    }
    short8 wb1[2][4];
    #pragma unroll
    for (int s = 0; s < 2; ++s)
        #pragma unroll
        for (int nt = 0; nt < 4; ++nt) {
            short8 v;
            #pragma unroll
            for (int j = 0; j < 8; ++j)
                v[j] = (short)f2bf(W1b[(s * 32 + quad * 8 + j) * 64 + nt * 16 + qm]);
            wb1[s][nt] = v;
        }
    float ba[4], bb[4];
    #pragma unroll
    for (int nt = 0; nt < 4; ++nt) { ba[nt] = b1a[nt * 16 + qm]; bb[nt] = b1b[nt * 16 + qm]; }

    short8 af1 = (short8)0;
    if (quad == 0 && node < NN) {
        const float4 za = *(const float4*)(z1 + (size_t)node * 8);
        const float4 zbv = *(const float4*)(z1 + (size_t)node * 8 + 4);
        af1[0] = (short)f2bf(za.x); af1[1] = (short)f2bf(za.y);
        af1[2] = (short)f2bf(za.z); af1[3] = (short)f2bf(za.w);
        af1[4] = (short)f2bf(zbv.x); af1[5] = (short)f2bf(zbv.y);
        af1[6] = (short)f2bf(zbv.z); af1[7] = (short)f2bf(zbv.w);
    }
    float4v acc[4];
    #pragma unroll
    for (int nt = 0; nt < 4; ++nt) {
        acc[nt] = (float4v){0.f, 0.f, 0.f, 0.f};
        acc[nt] = __builtin_amdgcn_mfma_f32_16x16x32_bf16(af1, wa1n[nt], acc[nt], 0, 0, 0);
    }
    #pragma unroll
    for (int nt = 0; nt < 4; ++nt)
        #pragma unroll
        for (int r = 0; r < 4; ++r)
            sT[(w * 16 + quad * 4 + r) * MSTRIDE + nt * 16 + qm] =
                (ushort)f2bf(fmaxf(acc[nt][r] + ba[nt], 0.f));
    __syncthreads();

    #pragma unroll
    for (int nt = 0; nt < 4; ++nt) acc[nt] = (float4v){0.f, 0.f, 0.f, 0.f};
    #pragma unroll
    for (int s = 0; s < 2; ++s) {
        short8 af = *(const short8*)&sT[(w * 16 + qm) * MSTRIDE + s * 32 + quad * 8];
        #pragma unroll
        for (int nt = 0; nt < 4; ++nt)
            acc[nt] = __builtin_amdgcn_mfma_f32_16x16x32_bf16(af, wb1[s][nt], acc[nt], 0, 0, 0);
    }
    #pragma unroll
    for (int nt = 0; nt < 4; ++nt)
        #pragma unroll
        for (int r = 0; r < 4; ++r)
            sO[(w * 16 + quad * 4 + r) * 64 + nt * 16 + qm] =
                (ushort)f2bf(fmaxf(acc[nt][r] + bb[nt], 0.f));
    __syncthreads();
    for (int i = t; i < 64 * 32; i += 256) {
        int nd = i >> 5;
        if (n0 + nd < NN) h1u[(size_t)(n0 + nd) * 32 + (i & 31)] = ((const uint*)sO)[i];
    }
}

// ---------- Layer 2 aggregation: 2 dims/lane, 16 edges (8 dword gathers) in flight ----------
__global__ __launch_bounds__(256) void aggr2_kernel(
    const uint* __restrict__ h1u,
    const uint* __restrict__ p0, const uint* __restrict__ p1, const uint* __restrict__ p2,
    const int* __restrict__ offs,
    const float* __restrict__ We2, const float* __restrict__ be2,
    uint* __restrict__ zb)
{
    __shared__ float sWe[256];
    __shared__ float sbe[64];
    int tid = threadIdx.x;
    sWe[tid] = We2[tid];
    if (tid < 64) sbe[tid] = be2[tid];
    __syncthreads();
    const int w = tid >> 6, lane = tid & 63;
    const int l = lane & 31;
    const int half8 = (lane >> 5) << 3;
    const int n = blockIdx.x * 4 + w;
    const int off = offs[n];
    const int deg = offs[n + 1] - off;
    const float w0x = sWe[2 * l],       w0y = sWe[2 * l + 1];
    const float w1x = sWe[64 + 2 * l],  w1y = sWe[64 + 2 * l + 1];
    const float w2x = sWe[128 + 2 * l], w2y = sWe[128 + 2 * l + 1];
    const float w3x = sWe[192 + 2 * l], w3y = sWe[192 + 2 * l + 1];
    const float bbx = sbe[2 * l],       bby = sbe[2 * l + 1];

    float accx = 0.f, accy = 0.f;
    for (int jb = 0; jb < deg; jb += 16) {
        int m = deg - jb;
        int ll = (lane < 16) ? ((lane < m) ? lane : 0) : 0;
        int idx = off + jb + ll;
        int sx = (int)(p0[idx] & 0xFFFFu);
        uint e01 = p1[idx];
        uint e23 = p2[idx];
        uint g[8];
        #pragma unroll
        for (int k = 0; k < 8; ++k) {
            int mk = k + half8;
            int sk = __shfl(sx, (mk < m) ? mk : 0);
            g[k] = h1u[(size_t)sk * 32 + l];
        }
        #pragma unroll
        for (int k = 0; k < 8; ++k) {
            int mk = k + half8;
            int sl = (mk < m) ? mk : 0;
            uint py = (uint)__shfl((int)e01, sl);
            uint pz = (uint)__shfl((int)e23, sl);
            float e0 = bf2f_lo(py), e1 = bf2f_hi(py);
            float e2 = bf2f_lo(pz), e3 = bf2f_hi(pz);
            float bx = bbx + e0 * w0x + e1 * w1x + e2 * w2x + e3 * w3x;
            float by = bby + e0 * w0y + e1 * w1y + e2 * w2y + e3 * w3y;
            float tx = fmaxf(bf2f_lo(g[k]) + bx, 0.f);
            float ty = fmaxf(bf2f_hi(g[k]) + by, 0.f);
            if (mk < m) { accx += tx; accy += ty; }
        }
    }
    accx += __shfl_xor(accx, 32);
    accy += __shfl_xor(accy, 32);
    if (lane < 32) {
        uint sw = h1u[(size_t)n * 32 + l];
        float zx = bf2f_lo(sw) + accx;
        float zy = bf2f_hi(sw) + accy;
        zb[(size_t)n * 32 + l] = f2bf(zx) | (f2bf(zy) << 16);
    }
}

// ---------- Layer 2 MLP via MFMA + segmented-reduction pooling ----------
__global__ __launch_bounds__(256) void mlp2_kernel(
    const uint* __restrict__ zb,
    const float* __restrict__ W2a, const float* __restrict__ b2a,
    const float* __restrict__ W2b, const float* __restrict__ b2b,
    const int* __restrict__ batch,
    float* __restrict__ sums, float* __restrict__ cnt)
{
    __shared__ __align__(16) ushort sT[64 * MSTRIDE];
    __shared__ float sH[64 * 64];
    __shared__ int sB[64];
    __shared__ float pbuf[4][64];
    __shared__ int pcnt[4];
    const int t = threadIdx.x;
    const int w = t >> 6, lane = t & 63;
    const int qm = lane & 15, quad = lane >> 4;
    const int n0 = blockIdx.x * 64;
    const int node = n0 + w * 16 + qm;
    const int nv = (NN - n0 < 64) ? (NN - n0) : 64;

    if (t < 64) sB[t] = (n0 + t < NN) ? batch[n0 + t] : -2;

    short8 wa[2][4], wb[2][4];
    #pragma unroll
    for (int s = 0; s < 2; ++s)
        #pragma unroll
        for (int nt = 0; nt < 4; ++nt) {
            short8 va, vb;
            #pragma unroll
            for (int j = 0; j < 8; ++j) {
                int k = s * 32 + quad * 8 + j, n = nt * 16 + qm;
                va[j] = (short)f2bf(W2a[k * 64 + n]);
                vb[j] = (short)f2bf(W2b[k * 64 + n]);
            }
            wa[s][nt] = va; wb[s][nt] = vb;
        }
    float ba[4], bb[4];
    #pragma unroll
    for (int nt = 0; nt < 4; ++nt) { ba[nt] = b2a[nt * 16 + qm]; bb[nt] = b2b[nt * 16 + qm]; }

    float4v acc[4];
    #pragma unroll
    for (int nt = 0; nt < 4; ++nt) acc[nt] = (float4v){0.f, 0.f, 0.f, 0.f};
    #pragma unroll
    for (int s = 0; s < 2; ++s) {
        uint4 zw = (node < NN) ? *(const uint4*)&zb[(size_t)node * 32 + s * 16 + quad * 4]
                               : make_uint4(0, 0, 0, 0);
        short8 af;
        *(uint4*)&af = zw;
        #pragma unroll
        for (int nt = 0; nt < 4; ++nt)
            acc[nt] = __builtin_amdgcn_mfma_f32_16x16x32_bf16(af, wa[s][nt], acc[nt], 0, 0, 0);
    }
    #pragma unroll
    for (int nt = 0; nt < 4; ++nt)
        #pragma unroll
        for (int r = 0; r < 4; ++r)
            sT[(w * 16 + quad * 4 + r) * MSTRIDE + nt * 16 + qm] =
                (ushort)f2bf(fmaxf(acc[nt][r] + ba[nt], 0.f));
    __syncthreads();

    #pragma unroll
    for (int nt = 0; nt < 4; ++nt) acc[nt] = (float4v){0.f, 0.f, 0.f, 0.f};
    #pragma unroll
    for (int s = 0; s < 2; ++s) {
        short8 af = *(const short8*)&sT[(w * 16 + qm) * MSTRIDE + s * 32 + quad * 8];
        #pragma unroll
        for (int nt = 0; nt < 4; ++nt)
            acc[nt] = __builtin_amdgcn_mfma_f32_16x16x32_bf16(af, wb[s][nt], acc[nt], 0, 0, 0);
    }
    #pragma unroll
    for (int nt = 0; nt < 4; ++nt)
        #pragma unroll
        for (int r = 0; r < 4; ++r)
            sH[(w * 16 + quad * 4 + r) * 64 + nt * 16 + qm] = fmaxf(acc[nt][r] + bb[nt], 0.f);
    __syncthreads();

    const int glo = sB[0];
    const int ghi = sB[nv - 1];
    const int c = t >> 6, d = t & 63;
    for (int g = glo; g <= ghi; ++g) {
        float p = 0.f;
        int lc = 0;
        #pragma unroll 4
        for (int i = 0; i < 16; ++i) {
            int nd = c * 16 + i;
            if (sB[nd] == g) { p += sH[nd * 64 + d]; ++lc; }
        }
        pbuf[c][d] = p;
        if (d == 0) pcnt[c] = lc;
        __syncthreads();
        int tc = pcnt[0] + pcnt[1] + pcnt[2] + pcnt[3];
        if (tc > 0) {
            if (c == 0) {
                float tot = pbuf[0][d] + pbuf[1][d] + pbuf[2][d] + pbuf[3][d];
                atomicAdd(&sums[(size_t)g * 64 + d], tot);
            }
            if (t == 0) atomicAdd(&cnt[g], (float)tc);
        }
        __syncthreads();
    }
}

// ---------- FC ----------
__global__ __launch_bounds__(256) void fc_kernel(
    const float* __restrict__ sums, const float* __restrict__ cnt,
    const float* __restrict__ Wfc, const float* __restrict__ bfc,
    float* __restrict__ out)
{
    int gid = blockIdx.x * blockDim.x + threadIdx.x;
    if (gid >= NG * 12) return;
    int g = gid / 12, jj = gid - g * 12;
    float inv = 1.f / fmaxf(cnt[g], 1.f);
    float acc = bfc[jj];
    #pragma unroll 8
    for (int k = 0; k < 64; ++k) acc += sums[(size_t)g * 64 + k] * inv * Wfc[k * 12 + jj];
    out[gid] = acc;
}

extern "C" void kernel_launch(void* const* d_in, const int* in_sizes, int n_in,
                              void* d_out, int out_size, void* d_ws, size_t ws_size,
                              hipStream_t stream)
{
    (void)in_sizes; (void)n_in; (void)out_size; (void)ws_size;
    const float*  x    = (const float*)d_in[0];
    const float4* ea   = (const float4*)d_in[1];
    const int*    eidx = (const int*)d_in[2];
    const int*    batch= (const int*)d_in[3];
    const float*  We1  = (const float*)d_in[4];
    const float*  be1  = (const float*)d_in[5];
    const float*  W1a  = (const float*)d_in[6];
    const float*  b1a  = (const float*)d_in[7];
    const float*  W1b  = (const float*)d_in[8];
    const float*  b1b  = (const float*)d_in[9];
    const float*  We2  = (const float*)d_in[10];
    const float*  be2  = (const float*)d_in[11];
    const float*  W2a  = (const float*)d_in[12];
    const float*  b2a  = (const float*)d_in[13];
    const float*  W2b  = (const float*)d_in[14];
    const float*  b2b  = (const float*)d_in[15];
    const float*  Wfc  = (const float*)d_in[16];
    const float*  bfc  = (const float*)d_in[17];
    float* out = (float*)d_out;
    float* ws  = (float*)d_ws;

    int*   bcnt  = (int*)(ws + OFF_BCNT);
    float* sums  = ws + OFF_SUMS;
    float* cnt   = ws + OFF_CNT;
    int*   bbase = (int*)(ws + OFF_BBASE);
    int*   bcur  = (int*)(ws + OFF_BCUR);
    int*   offs  = (int*)(ws + OFF_OFFS);
    uint*  p0    = (uint*)(ws + OFF_P0);
    uint*  p1    = (uint*)(ws + OFF_P1);
    uint*  p2    = (uint*)(ws + OFF_P2);
    float* z1    = ws + OFF_Z1;
    uint*  h1u   = (uint*)(ws + OFF_H1);
    uint*  zb    = (uint*)(ws + OFF_Z);

    hipMemsetAsync(d_ws, 0, (size_t)ZERO_UNITS * 4, stream);

    bhist_kernel<<<256, 256, 0, stream>>>(eidx, bcnt);
    bscan_kernel<<<1, 256, 0, stream>>>(bcnt, bbase, bcur);
    bin_kernel  <<<NTILE, 256, 0, stream>>>(eidx, ea, bcur, p0, p1, p2);
    build_kernel<<<NB2, 256, 0, stream>>>(bbase, bcnt, offs, p0, p1, p2);
    aggr1_kernel<<<2500, 256, 0, stream>>>(x, p0, p1, p2, offs, We1, be1, z1);
    node1_kernel<<<(NN + 63) / 64, 256, 0, stream>>>(z1, W1a, b1a, W1b, b1b, h1u);
    aggr2_kernel<<<12500, 256, 0, stream>>>(h1u, p0, p1, p2, offs, We2, be2, zb);
    mlp2_kernel <<<(NN + 63) / 64, 256, 0, stream>>>(zb, W2a, b2a, W2b, b2b, batch, sums, cnt);
    fc_kernel   <<<(NG * 12 + 255) / 256, 256, 0, stream>>>(sums, cnt, Wfc, bfc, out);
}